// Round 10
// baseline (47.027 us; speedup 1.0000x reference)
//
#include <hip/hip_runtime.h>
#include <hip/hip_bf16.h>

#define UNITS 1024
#define DIN   2048
#define KCONN 16
#define BATCH 4096
#define BB    8   // batch rows per tile in kernel 2

typedef float    f32x4 __attribute__((ext_vector_type(4)));
typedef unsigned u32x4 __attribute__((ext_vector_type(4)));
typedef int      i32x4 __attribute__((ext_vector_type(4)));

#define LDNT4F(P) __builtin_nontemporal_load((const f32x4*)(P))

// ---------------------------------------------------------------------------
// Kernel 1: EXACT round-5 proven version (26.55 us paired with kernel 2).
// Per-unit top-16 of P = D + GN (register-resident), sign(W) fused.
// One wave per unit; DPP wave-argmax + owner pop. Zero LDS.
// ---------------------------------------------------------------------------
__global__ __launch_bounds__(256) void topk_sel_kernel(
    const float* __restrict__ Dl, const float* __restrict__ GN,
    const float* __restrict__ W, int* __restrict__ selP) {
  const int lane = threadIdx.x & 63;
  const int wv   = threadIdx.x >> 6;
  const int u    = blockIdx.x * 4 + wv;

  // lane owns features g(l) = (l>>2)*256 + lane*4 + (l&3), l = 0..31
  const f32x4* D4 = (const f32x4*)(Dl + (size_t)u * DIN);
  const f32x4* G4 = (const f32x4*)(GN + (size_t)u * DIN);
  float v[32];
#pragma unroll
  for (int i4 = 0; i4 < 8; ++i4) {
    f32x4 d = LDNT4F(D4 + i4 * 64 + lane);
    f32x4 g = LDNT4F(G4 + i4 * 64 + lane);
    v[i4 * 4 + 0] = d[0] + g[0];
    v[i4 * 4 + 1] = d[1] + g[1];
    v[i4 * 4 + 2] = d[2] + g[2];
    v[i4 * 4 + 3] = d[3] + g[3];
  }

  // per-lane top-2 (strict > => lowest-l wins ties)
  float m1 = -INFINITY, m2 = -INFINITY;
  int   l1 = 0, l2 = 0;
#pragma unroll
  for (int l = 0; l < 32; ++l) {
    float xv = v[l];
    bool g1t = xv > m1;
    bool g2t = xv > m2;
    m2 = g1t ? m1 : (g2t ? xv : m2);
    l2 = g1t ? l1 : (g2t ? l : l2);
    m1 = g1t ? xv : m1;
    l1 = g1t ? l  : l1;
  }

  unsigned claimed = 0;
  int navail = 2;
  int gsel = 0;          // lane j holds winner-g of iteration j

#pragma unroll 1
  for (int it = 0; it < KCONN; ++it) {
    unsigned kb = __float_as_uint(m1);
    unsigned kv = kb ^ (((int)kb < 0) ? 0xFFFFFFFFu : 0x80000000u);
    int g1 = ((l1 >> 2) << 8) | (lane << 2) | (l1 & 3);   // unique per lane
    unsigned rk = kv; int rg = g1;
#define DSTEP(CTRL, RM) { \
    unsigned k2_ = (unsigned)__builtin_amdgcn_update_dpp((int)rk, (int)rk, CTRL, RM, 0xF, false); \
    int g2_ = __builtin_amdgcn_update_dpp(rg, rg, CTRL, RM, 0xF, false); \
    bool tk_ = (k2_ > rk) || ((k2_ == rk) && (g2_ < rg)); \
    rk = tk_ ? k2_ : rk; rg = tk_ ? g2_ : rg; }
    DSTEP(0x111, 0xF)   // row_shr:1
    DSTEP(0x112, 0xF)   // row_shr:2
    DSTEP(0x114, 0xF)   // row_shr:4
    DSTEP(0x118, 0xF)   // row_shr:8
    DSTEP(0x142, 0xA)   // row_bcast:15 -> rows 1,3
    DSTEP(0x143, 0xC)   // row_bcast:31 -> rows 2,3
#undef DSTEP
    int wg = __builtin_amdgcn_readlane(rg, 63);           // wave-uniform winner
    if (lane == it) gsel = wg;

    bool own  = (g1 == wg);
    bool need = own && (navail == 1);
    if (own) claimed |= 1u << l1;
    if (own && navail == 2) { m1 = m2; l1 = l2; navail = 1; }
    if (need) {                                           // rare owner rescan
      float bm = -INFINITY; int bl = 0;
#pragma unroll
      for (int l = 0; l < 32; ++l) {
        float xv = (claimed & (1u << l)) ? -INFINITY : v[l];
        if (xv > bm) { bm = xv; bl = l; }
      }
      m1 = bm; l1 = bl;
    }
  }

  if (lane < KCONN) {
    int g = gsel;
    float w = W[(size_t)u * DIN + g];
    int sd = g ^ ((g >> 3) & 7);                          // swizzled chunk
    int pa = (w == 0.0f) ? (DIN << 1)
                         : ((sd << 1) | (w < 0.0f ? 1 : 0));
    selP[u * KCONN + lane] = pa;
  }
}

// ---------------------------------------------------------------------------
// Kernel 2: EXACT round-5 proven version. y[b,u] = sum_j sign_j * x[b,idx_j]
// bf16-packed transposed LDS tile (XOR-swizzled chunks), zero sink at
// xs[DIN], sign via XOR 0x80008000, float adds. 512 threads, grid 512.
// ---------------------------------------------------------------------------
__global__ __launch_bounds__(512) void gather_mm_kernel(
    const float* __restrict__ x, const int* __restrict__ selP,
    float* __restrict__ y) {
  __shared__ u32x4 xs[DIN + 1];        // 32 KB + 16B
  const int t = threadIdx.x;
  const size_t b0 = (size_t)blockIdx.x * BB;

  // sel prefetch for units t and t+512 (in flight under staging)
  const i32x4* S0 = (const i32x4*)(selP + t * KCONN);
  const i32x4* S1 = (const i32x4*)(selP + (t + 512) * KCONN);
  i32x4 sA0 = S0[0], sA1 = S0[1], sA2 = S0[2], sA3 = S0[3];
  i32x4 sB0 = S1[0], sB1 = S1[1], sB2 = S1[2], sB3 = S1[3];

  // ---- stage: thread t owns features 4t..4t+3, builds whole 16B chunks ----
  const float* xb = x + b0 * DIN + 4 * t;
  f32x4 r0 = LDNT4F(xb + 0 * DIN);
  f32x4 r1 = LDNT4F(xb + 1 * DIN);
  f32x4 r2 = LDNT4F(xb + 2 * DIN);
  f32x4 r3 = LDNT4F(xb + 3 * DIN);
  f32x4 r4 = LDNT4F(xb + 4 * DIN);
  f32x4 r5 = LDNT4F(xb + 5 * DIN);
  f32x4 r6 = LDNT4F(xb + 6 * DIN);
  f32x4 r7 = LDNT4F(xb + 7 * DIN);

#define PK2(LO, HI) ({ __hip_bfloat16 l_ = __float2bfloat16(LO), h_ = __float2bfloat16(HI); \
  (unsigned)(*(unsigned short*)&l_) | ((unsigned)(*(unsigned short*)&h_) << 16); })
#pragma unroll
  for (int j = 0; j < 4; ++j) {
    const int d  = 4 * t + j;
    const int sd = d ^ ((d >> 3) & 7);
    u32x4 ch;
    ch[0] = PK2(r0[j], r1[j]);
    ch[1] = PK2(r2[j], r3[j]);
    ch[2] = PK2(r4[j], r5[j]);
    ch[3] = PK2(r6[j], r7[j]);
    xs[sd] = ch;
  }
#undef PK2
  if (t == 0) { u32x4 z = {0, 0, 0, 0}; xs[DIN] = z; }   // zero-weight sink
  __syncthreads();

  // ---- gather + accumulate ----
#define GJ(PA) { unsigned pa_ = (unsigned)(PA); \
  u32x4 vv_ = xs[pa_ >> 1]; \
  unsigned sm_ = (pa_ & 1u) ? 0x80008000u : 0u; \
  vv_[0] ^= sm_; vv_[1] ^= sm_; vv_[2] ^= sm_; vv_[3] ^= sm_; \
  a0 += __uint_as_float(vv_[0] << 16); a1 += __uint_as_float(vv_[0] & 0xffff0000u); \
  a2 += __uint_as_float(vv_[1] << 16); a3 += __uint_as_float(vv_[1] & 0xffff0000u); \
  a4 += __uint_as_float(vv_[2] << 16); a5 += __uint_as_float(vv_[2] & 0xffff0000u); \
  a6 += __uint_as_float(vv_[3] << 16); a7 += __uint_as_float(vv_[3] & 0xffff0000u); }

#define UNIT(SA, SB, SC, SD, U) { \
  float a0 = 0, a1 = 0, a2 = 0, a3 = 0, a4 = 0, a5 = 0, a6 = 0, a7 = 0; \
  GJ(SA[0]) GJ(SA[1]) GJ(SA[2]) GJ(SA[3]) \
  GJ(SB[0]) GJ(SB[1]) GJ(SB[2]) GJ(SB[3]) \
  GJ(SC[0]) GJ(SC[1]) GJ(SC[2]) GJ(SC[3]) \
  GJ(SD[0]) GJ(SD[1]) GJ(SD[2]) GJ(SD[3]) \
  const int u_ = (U); \
  __builtin_nontemporal_store(a0, &y[(b0 + 0) * UNITS + u_]); \
  __builtin_nontemporal_store(a1, &y[(b0 + 1) * UNITS + u_]); \
  __builtin_nontemporal_store(a2, &y[(b0 + 2) * UNITS + u_]); \
  __builtin_nontemporal_store(a3, &y[(b0 + 3) * UNITS + u_]); \
  __builtin_nontemporal_store(a4, &y[(b0 + 4) * UNITS + u_]); \
  __builtin_nontemporal_store(a5, &y[(b0 + 5) * UNITS + u_]); \
  __builtin_nontemporal_store(a6, &y[(b0 + 6) * UNITS + u_]); \
  __builtin_nontemporal_store(a7, &y[(b0 + 7) * UNITS + u_]); }

  UNIT(sA0, sA1, sA2, sA3, t)
  UNIT(sB0, sB1, sB2, sB3, t + 512)
#undef UNIT
#undef GJ
}

// ---------------------------------------------------------------------------
// PROBE ROUND: launch k1,k1,k2,k2 (both idempotent -> identical output).
// dur - 26.55us isolates device time (k1+k2) + 2 small gaps, splitting
// "device-bound" from "fixed replay overhead" decisively.
// ---------------------------------------------------------------------------
extern "C" void kernel_launch(void* const* d_in, const int* in_sizes, int n_in,
                              void* d_out, int out_size, void* d_ws, size_t ws_size,
                              hipStream_t stream) {
  const float* x  = (const float*)d_in[0];   // [4096, 2048]
  const float* W  = (const float*)d_in[1];   // [1024, 2048]
  const float* Dl = (const float*)d_in[2];   // [1024, 2048]
  const float* GN = (const float*)d_in[3];   // [1, 1024, 2048]
  float* y = (float*)d_out;                  // [4096, 1024]

  int* selP = (int*)d_ws;                    // 1024*16 packed ints

  topk_sel_kernel<<<UNITS / 4, 256, 0, stream>>>(Dl, GN, W, selP);
  topk_sel_kernel<<<UNITS / 4, 256, 0, stream>>>(Dl, GN, W, selP);
  gather_mm_kernel<<<BATCH / BB, 512, 0, stream>>>(x, selP, y);
  gather_mm_kernel<<<BATCH / BB, 512, 0, stream>>>(x, selP, y);
}

// Round 12
// 26.450 us; speedup vs baseline: 1.7780x; 1.7780x over previous
//
#include <hip/hip_runtime.h>
#include <hip/hip_bf16.h>

#define UNITS 1024
#define DIN   2048
#define KCONN 16
#define BATCH 4096
#define BB    8   // batch rows per tile in kernel 2

typedef float    f32x4 __attribute__((ext_vector_type(4)));
typedef unsigned u32x4 __attribute__((ext_vector_type(4)));
typedef int      i32x4 __attribute__((ext_vector_type(4)));

#define LDNT4F(P) __builtin_nontemporal_load((const f32x4*)(P))

// ---------------------------------------------------------------------------
// Kernel 1: EXACT round-5 proven version (26.55 us total, absmax 0.125).
// Per-unit top-16 of P = D + GN (register-resident), sign(W) fused.
// One wave per unit; DPP wave-argmax + owner pop. Zero LDS.
// Emits packed selection pa = (swizzled_chunk << 1) | (W<0); W==0 -> DIN<<1.
// ---------------------------------------------------------------------------
__global__ __launch_bounds__(256) void topk_sel_kernel(
    const float* __restrict__ Dl, const float* __restrict__ GN,
    const float* __restrict__ W, int* __restrict__ selP) {
  const int lane = threadIdx.x & 63;
  const int wv   = threadIdx.x >> 6;
  const int u    = blockIdx.x * 4 + wv;

  // lane owns features g(l) = (l>>2)*256 + lane*4 + (l&3), l = 0..31
  const f32x4* D4 = (const f32x4*)(Dl + (size_t)u * DIN);
  const f32x4* G4 = (const f32x4*)(GN + (size_t)u * DIN);
  float v[32];
#pragma unroll
  for (int i4 = 0; i4 < 8; ++i4) {
    f32x4 d = LDNT4F(D4 + i4 * 64 + lane);
    f32x4 g = LDNT4F(G4 + i4 * 64 + lane);
    v[i4 * 4 + 0] = d[0] + g[0];
    v[i4 * 4 + 1] = d[1] + g[1];
    v[i4 * 4 + 2] = d[2] + g[2];
    v[i4 * 4 + 3] = d[3] + g[3];
  }

  // per-lane top-2 (strict > => lowest-l wins ties)
  float m1 = -INFINITY, m2 = -INFINITY;
  int   l1 = 0, l2 = 0;
#pragma unroll
  for (int l = 0; l < 32; ++l) {
    float xv = v[l];
    bool g1t = xv > m1;
    bool g2t = xv > m2;
    m2 = g1t ? m1 : (g2t ? xv : m2);
    l2 = g1t ? l1 : (g2t ? l : l2);
    m1 = g1t ? xv : m1;
    l1 = g1t ? l  : l1;
  }

  unsigned claimed = 0;
  int navail = 2;        // 2: m1,m2 valid; 1: only m1 valid
  int gsel = 0;          // lane j holds winner-g of iteration j

#pragma unroll 1
  for (int it = 0; it < KCONN; ++it) {
    unsigned kb = __float_as_uint(m1);
    unsigned kv = kb ^ (((int)kb < 0) ? 0xFFFFFFFFu : 0x80000000u);
    int g1 = ((l1 >> 2) << 8) | (lane << 2) | (l1 & 3);   // unique per lane
    unsigned rk = kv; int rg = g1;
#define DSTEP(CTRL, RM) { \
    unsigned k2_ = (unsigned)__builtin_amdgcn_update_dpp((int)rk, (int)rk, CTRL, RM, 0xF, false); \
    int g2_ = __builtin_amdgcn_update_dpp(rg, rg, CTRL, RM, 0xF, false); \
    bool tk_ = (k2_ > rk) || ((k2_ == rk) && (g2_ < rg)); \
    rk = tk_ ? k2_ : rk; rg = tk_ ? g2_ : rg; }
    DSTEP(0x111, 0xF)   // row_shr:1
    DSTEP(0x112, 0xF)   // row_shr:2
    DSTEP(0x114, 0xF)   // row_shr:4
    DSTEP(0x118, 0xF)   // row_shr:8
    DSTEP(0x142, 0xA)   // row_bcast:15 -> rows 1,3
    DSTEP(0x143, 0xC)   // row_bcast:31 -> rows 2,3
#undef DSTEP
    int wg = __builtin_amdgcn_readlane(rg, 63);           // wave-uniform winner
    if (lane == it) gsel = wg;

    bool own  = (g1 == wg);
    bool need = own && (navail == 1);
    if (own) claimed |= 1u << l1;
    if (own && navail == 2) { m1 = m2; l1 = l2; navail = 1; }
    if (need) {                                           // rare owner rescan
      float bm = -INFINITY; int bl = 0;
#pragma unroll
      for (int l = 0; l < 32; ++l) {
        float xv = (claimed & (1u << l)) ? -INFINITY : v[l];
        if (xv > bm) { bm = xv; bl = l; }
      }
      m1 = bm; l1 = bl;
    }
  }

  if (lane < KCONN) {
    int g = gsel;
    float w = W[(size_t)u * DIN + g];
    int sd = g ^ ((g >> 3) & 7);                          // swizzled chunk
    int pa = (w == 0.0f) ? (DIN << 1)
                         : ((sd << 1) | (w < 0.0f ? 1 : 0));
    selP[u * KCONN + lane] = pa;
  }
}

// ---------------------------------------------------------------------------
// Kernel 2: EXACT round-5 proven version. y[b,u] = sum_j sign_j * x[b,idx_j]
// bf16-packed transposed LDS tile (XOR-swizzled chunks), zero sink at
// xs[DIN], sign via XOR 0x80008000, float adds. 512 threads, grid 512,
// 2 blocks/CU (stage || gather overlap across blocks).
// ---------------------------------------------------------------------------
__global__ __launch_bounds__(512) void gather_mm_kernel(
    const float* __restrict__ x, const int* __restrict__ selP,
    float* __restrict__ y) {
  __shared__ u32x4 xs[DIN + 1];        // 32 KB + 16B
  const int t = threadIdx.x;
  const size_t b0 = (size_t)blockIdx.x * BB;

  // sel prefetch for units t and t+512 (in flight under staging)
  const i32x4* S0 = (const i32x4*)(selP + t * KCONN);
  const i32x4* S1 = (const i32x4*)(selP + (t + 512) * KCONN);
  i32x4 sA0 = S0[0], sA1 = S0[1], sA2 = S0[2], sA3 = S0[3];
  i32x4 sB0 = S1[0], sB1 = S1[1], sB2 = S1[2], sB3 = S1[3];

  // ---- stage: thread t owns features 4t..4t+3, builds whole 16B chunks ----
  const float* xb = x + b0 * DIN + 4 * t;
  f32x4 r0 = LDNT4F(xb + 0 * DIN);
  f32x4 r1 = LDNT4F(xb + 1 * DIN);
  f32x4 r2 = LDNT4F(xb + 2 * DIN);
  f32x4 r3 = LDNT4F(xb + 3 * DIN);
  f32x4 r4 = LDNT4F(xb + 4 * DIN);
  f32x4 r5 = LDNT4F(xb + 5 * DIN);
  f32x4 r6 = LDNT4F(xb + 6 * DIN);
  f32x4 r7 = LDNT4F(xb + 7 * DIN);

#define PK2(LO, HI) ({ __hip_bfloat16 l_ = __float2bfloat16(LO), h_ = __float2bfloat16(HI); \
  (unsigned)(*(unsigned short*)&l_) | ((unsigned)(*(unsigned short*)&h_) << 16); })
#pragma unroll
  for (int j = 0; j < 4; ++j) {
    const int d  = 4 * t + j;
    const int sd = d ^ ((d >> 3) & 7);
    u32x4 ch;
    ch[0] = PK2(r0[j], r1[j]);
    ch[1] = PK2(r2[j], r3[j]);
    ch[2] = PK2(r4[j], r5[j]);
    ch[3] = PK2(r6[j], r7[j]);
    xs[sd] = ch;
  }
#undef PK2
  if (t == 0) { u32x4 z = {0, 0, 0, 0}; xs[DIN] = z; }   // zero-weight sink
  __syncthreads();

  // ---- gather + accumulate ----
#define GJ(PA) { unsigned pa_ = (unsigned)(PA); \
  u32x4 vv_ = xs[pa_ >> 1]; \
  unsigned sm_ = (pa_ & 1u) ? 0x80008000u : 0u; \
  vv_[0] ^= sm_; vv_[1] ^= sm_; vv_[2] ^= sm_; vv_[3] ^= sm_; \
  a0 += __uint_as_float(vv_[0] << 16); a1 += __uint_as_float(vv_[0] & 0xffff0000u); \
  a2 += __uint_as_float(vv_[1] << 16); a3 += __uint_as_float(vv_[1] & 0xffff0000u); \
  a4 += __uint_as_float(vv_[2] << 16); a5 += __uint_as_float(vv_[2] & 0xffff0000u); \
  a6 += __uint_as_float(vv_[3] << 16); a7 += __uint_as_float(vv_[3] & 0xffff0000u); }

#define UNIT(SA, SB, SC, SD, U) { \
  float a0 = 0, a1 = 0, a2 = 0, a3 = 0, a4 = 0, a5 = 0, a6 = 0, a7 = 0; \
  GJ(SA[0]) GJ(SA[1]) GJ(SA[2]) GJ(SA[3]) \
  GJ(SB[0]) GJ(SB[1]) GJ(SB[2]) GJ(SB[3]) \
  GJ(SC[0]) GJ(SC[1]) GJ(SC[2]) GJ(SC[3]) \
  GJ(SD[0]) GJ(SD[1]) GJ(SD[2]) GJ(SD[3]) \
  const int u_ = (U); \
  __builtin_nontemporal_store(a0, &y[(b0 + 0) * UNITS + u_]); \
  __builtin_nontemporal_store(a1, &y[(b0 + 1) * UNITS + u_]); \
  __builtin_nontemporal_store(a2, &y[(b0 + 2) * UNITS + u_]); \
  __builtin_nontemporal_store(a3, &y[(b0 + 3) * UNITS + u_]); \
  __builtin_nontemporal_store(a4, &y[(b0 + 4) * UNITS + u_]); \
  __builtin_nontemporal_store(a5, &y[(b0 + 5) * UNITS + u_]); \
  __builtin_nontemporal_store(a6, &y[(b0 + 6) * UNITS + u_]); \
  __builtin_nontemporal_store(a7, &y[(b0 + 7) * UNITS + u_]); }

  UNIT(sA0, sA1, sA2, sA3, t)
  UNIT(sB0, sB1, sB2, sB3, t + 512)
#undef UNIT
#undef GJ
}

// ---------------------------------------------------------------------------
extern "C" void kernel_launch(void* const* d_in, const int* in_sizes, int n_in,
                              void* d_out, int out_size, void* d_ws, size_t ws_size,
                              hipStream_t stream) {
  const float* x  = (const float*)d_in[0];   // [4096, 2048]
  const float* W  = (const float*)d_in[1];   // [1024, 2048]
  const float* Dl = (const float*)d_in[2];   // [1024, 2048]
  const float* GN = (const float*)d_in[3];   // [1, 1024, 2048]
  float* y = (float*)d_out;                  // [4096, 1024]

  int* selP = (int*)d_ws;                    // 1024*16 packed ints

  topk_sel_kernel<<<UNITS / 4, 256, 0, stream>>>(Dl, GN, W, selP);
  gather_mm_kernel<<<BATCH / BB, 512, 0, stream>>>(x, selP, y);
}